// Round 15
// baseline (213.053 us; speedup 1.0000x reference)
//
#include <hip/hip_runtime.h>
#include <hip/hip_bf16.h>

#define EDIM  128
#define QN    32
#define DN    256
#define NK    11
#define REP   5     // probe: repeat to push each dispatch above fillBuffer rows

typedef __attribute__((ext_vector_type(8))) short bf16x8;
typedef __attribute__((ext_vector_type(4))) float f32x4;

#define EXP2F(x) __builtin_amdgcn_exp2f(x)

template <int CTRL>
static __device__ inline float dpp_add(float x) {
    int y = __builtin_amdgcn_update_dpp(0, __float_as_int(x), CTRL, 0xF, 0xF, true);
    return x + __int_as_float(y);
}
static __device__ inline float sum16(float x) {
    x = dpp_add<0xB1>(x);
    x = dpp_add<0x4E>(x);
    x = dpp_add<0x124>(x);
    x = dpp_add<0x128>(x);
    return x;
}

static __device__ inline int swz(int r, int c) { return c ^ ((r & 7) << 4); }

static __device__ inline bf16x8 pack8(float4 a, float4 b) {
    union { bf16x8 v; __hip_bfloat16 h[8]; } u;
    u.h[0] = __float2bfloat16(a.x); u.h[1] = __float2bfloat16(a.y);
    u.h[2] = __float2bfloat16(a.z); u.h[3] = __float2bfloat16(a.w);
    u.h[4] = __float2bfloat16(b.x); u.h[5] = __float2bfloat16(b.y);
    u.h[6] = __float2bfloat16(b.z); u.h[7] = __float2bfloat16(b.w);
    return u.v;
}
static __device__ inline float sumsq8(float4 a, float4 b) {
    float s = a.x * a.x + a.y * a.y + a.z * a.z + a.w * a.w;
    s = fmaf(b.x, b.x, s); s = fmaf(b.y, b.y, s);
    s = fmaf(b.z, b.z, s); s = fmaf(b.w, b.w, s);
    return s;
}

// V=0 full | V=1 no-eval | V=2 no-stage | V=3 no-reduce
template <int V>
__global__ __launch_bounds__(512, 4) void knrm_probe(const int* __restrict__ qtok,
                                                     const int* __restrict__ dtok,
                                                     const float* __restrict__ emb,
                                                     const float* __restrict__ fcw,
                                                     float* __restrict__ outp) {
    constexpr bool STAGE  = (V != 2);
    constexpr bool EVAL   = (V != 1);
    constexpr bool REDUCE = (V != 3);

    __shared__ __align__(16) unsigned short dbuf[DN * EDIM];
    __shared__ __align__(16) unsigned short qbuf[QN * EDIM];
    __shared__ float redS[8];

    const float C0 = 0.3989422804014327f;
    const float C1 = 7.30620157e-3f;
    const float C2 = 2.45119242e-6f;
    const float C3 = 1.50605972e-11f;
    const float C4 = 1.69484929e-18f;

    int b = blockIdx.x, tid = threadIdx.x;
    int w = tid >> 6, lane = tid & 63;
    int lr = lane & 15, lg = lane >> 4;
    int qt = w & 1, ds = w >> 1;

    const int* qtb = qtok + b * QN;
    const int* dtb = dtok + b * DN;

    for (int rep = 0; rep < REP; ++rep) {
        asm volatile("" ::: "memory");

        int tcurs[4], qtr[4];
        if constexpr (STAGE) {
            int tq = qtb[(w << 2) + lg];
            int tdA[4], tdB[4];
            #pragma unroll
            for (int it = 0; it < 4; ++it) {
                tdA[it] = dtb[(w << 4) + (it << 2) + lg];
                tdB[it] = dtb[128 + (w << 4) + (it << 2) + lg];
            }
            #pragma unroll
            for (int t = 0; t < 4; ++t) tcurs[t] = dtb[(t << 6) + (ds << 4) + lr];
            #pragma unroll
            for (int r = 0; r < 4; ++r) qtr[r] = qtb[(qt << 4) + (lg << 2) + r];

            const float4* qsrc = (const float4*)(emb + (size_t)tq * EDIM) + lr * 2;
            float4 qv0 = qsrc[0], qv1 = qsrc[1];
            float4 av[4][2], bv[4][2];
            #pragma unroll
            for (int it = 0; it < 4; ++it) {
                const float4* s0 = (const float4*)(emb + (size_t)tdA[it] * EDIM) + lr * 2;
                av[it][0] = s0[0]; av[it][1] = s0[1];
            }
            #pragma unroll
            for (int it = 0; it < 4; ++it) {
                const float4* s1 = (const float4*)(emb + (size_t)tdB[it] * EDIM) + lr * 2;
                bv[it][0] = s1[0]; bv[it][1] = s1[1];
            }
            {
                int qr = (w << 2) + lg;
                float inv = 1.0f / sqrtf(sum16(sumsq8(qv0, qv1)));
                qv0.x *= inv; qv0.y *= inv; qv0.z *= inv; qv0.w *= inv;
                qv1.x *= inv; qv1.y *= inv; qv1.z *= inv; qv1.w *= inv;
                *(bf16x8*)((char*)qbuf + qr * 256 + swz(qr, lr * 16)) = pack8(qv0, qv1);
            }
            #pragma unroll
            for (int it = 0; it < 4; ++it) {
                int r = (w << 4) + (it << 2) + lg;
                float inv = 1.0f / sqrtf(sum16(sumsq8(av[it][0], av[it][1])));
                float4 v0 = av[it][0], v1 = av[it][1];
                v0.x *= inv; v0.y *= inv; v0.z *= inv; v0.w *= inv;
                v1.x *= inv; v1.y *= inv; v1.z *= inv; v1.w *= inv;
                *(bf16x8*)((char*)dbuf + r * 256 + swz(r, lr * 16)) = pack8(v0, v1);
            }
            #pragma unroll
            for (int it = 0; it < 4; ++it) {
                int r = 128 + (w << 4) + (it << 2) + lg;
                float inv = 1.0f / sqrtf(sum16(sumsq8(bv[it][0], bv[it][1])));
                float4 v0 = bv[it][0], v1 = bv[it][1];
                v0.x *= inv; v0.y *= inv; v0.z *= inv; v0.w *= inv;
                v1.x *= inv; v1.y *= inv; v1.z *= inv; v1.w *= inv;
                *(bf16x8*)((char*)dbuf + r * 256 + swz(r, lr * 16)) = pack8(v0, v1);
            }
        } else {
            #pragma unroll
            for (int t = 0; t < 4; ++t) tcurs[t] = t + 1;
            #pragma unroll
            for (int r = 0; r < 4; ++r) qtr[r] = r + 1;
        }
        __syncthreads();                              // bar1

        bf16x8 A0, A1, A2, A3;
        {
            int qr = (qt << 4) + lr;
            const char* qb = (const char*)qbuf + qr * 256;
            A0 = *(const bf16x8*)(qb + swz(qr, lg * 16));
            A1 = *(const bf16x8*)(qb + swz(qr, lg * 16 + 64));
            A2 = *(const bf16x8*)(qb + swz(qr, lg * 16 + 128));
            A3 = *(const bf16x8*)(qb + swz(qr, lg * 16 + 192));
        }

        float kacc[4][NK];
        #pragma unroll
        for (int r = 0; r < 4; ++r)
            #pragma unroll
            for (int k = 0; k < NK; ++k) kacc[r][k] = 0.0f;

        #pragma unroll
        for (int t = 0; t < 4; ++t) {
            int dr = (t << 6) + (ds << 4) + lr;
            const char* db = (const char*)dbuf + dr * 256;
            bf16x8 B0 = *(const bf16x8*)(db + swz(dr, lg * 16));
            bf16x8 B1 = *(const bf16x8*)(db + swz(dr, lg * 16 + 64));
            bf16x8 B2 = *(const bf16x8*)(db + swz(dr, lg * 16 + 128));
            bf16x8 B3 = *(const bf16x8*)(db + swz(dr, lg * 16 + 192));
            int tcur = tcurs[t];

            f32x4 acc = {0.0f, 0.0f, 0.0f, 0.0f};
            acc = __builtin_amdgcn_mfma_f32_16x16x32_bf16(A0, B0, acc, 0, 0, 0);
            acc = __builtin_amdgcn_mfma_f32_16x16x32_bf16(A1, B1, acc, 0, 0, 0);
            acc = __builtin_amdgcn_mfma_f32_16x16x32_bf16(A2, B2, acc, 0, 0, 0);
            acc = __builtin_amdgcn_mfma_f32_16x16x32_bf16(A3, B3, acc, 0, 0, 0);

            if constexpr (EVAL) {
                bool dok = (tcur > 0);
                float mc = dok ? C0 : 0.0f;
                #pragma unroll
                for (int r = 0; r < 4; ++r) {
                    float t2 = acc[r];
                    kacc[r][0] += (tcur == qtr[r]) ? mc : 0.0f;
                    float d  = t2 - 0.1f;
                    float g  = EXP2F(d * d * -72.1347520f);
                    g = dok ? g : 0.0f;
                    float Em = EXP2F(t2 * -28.8539008f);
                    float Ep = EXP2F(t2 *  28.8539008f);
                    float h = g;
                    kacc[r][5]  += h * C0;
                    h *= Em; kacc[r][6]  += h * C0;
                    h *= Em; kacc[r][7]  += h * C1;
                    h *= Em; kacc[r][8]  += h * C2;
                    h *= Em; kacc[r][9]  += h * C3;
                    h *= Em; kacc[r][10] += h * C4;
                    h = g;
                    h *= Ep; kacc[r][4]  += h * C1;
                    h *= Ep; kacc[r][3]  += h * C2;
                    h *= Ep; kacc[r][2]  += h * C3;
                    h *= Ep; kacc[r][1]  += h * C4;
                }
            } else {
                #pragma unroll
                for (int r = 0; r < 4; ++r) kacc[r][0] += acc[r];   // keep MFMA live
            }
        }

        __syncthreads();                              // bar2
        float* part = (float*)qbuf;
        if constexpr (REDUCE) {
            #pragma unroll
            for (int r = 0; r < 4; ++r)
                #pragma unroll
                for (int k = 0; k < NK; ++k) kacc[r][k] = sum16(kacc[r][k]);
            if (lr == 0) {
                float* pw = part + w * (16 * NK) + (lg << 2) * NK;
                #pragma unroll
                for (int r = 0; r < 4; ++r)
                    #pragma unroll
                    for (int k = 0; k < NK; ++k)
                        pw[r * NK + k] = kacc[r][k];
            }
        } else {
            #pragma unroll
            for (int r = 0; r < 4; ++r)
                #pragma unroll
                for (int k = 0; k < NK; ++k)
                    asm volatile("" :: "v"(kacc[r][k]));  // keep eval live (rule #17)
        }
        __syncthreads();                              // bar3

        float total = 0.0f;
        if constexpr (REDUCE) {
            if (tid < QN * NK) {
                int q = tid / NK, k = tid - (tid / NK) * NK;
                int qt2 = q >> 4, row = q & 15;
                const float* pb = part + qt2 * (16 * NK) + row * NK + k;
                float v = pb[0] + pb[2 * 16 * NK] + pb[4 * 16 * NK] + pb[6 * 16 * NK];
                float m = (qtb[q] > 0) ? 1.0f : 0.0f;
                total = m * fcw[k] * __logf(fmaxf(v, 1e-10f));
            }
            #pragma unroll
            for (int off = 32; off; off >>= 1) total += __shfl_xor(total, off);
        }
        if (lane == 0) redS[w] = total;
        __syncthreads();                              // bar4
        if (tid == 0) {
            float s = 0.0f;
            #pragma unroll
            for (int i = 0; i < 8; ++i) s += redS[i];
            outp[b] = s;
        }
        __syncthreads();                              // qbuf reusable next rep
    }
}

extern "C" void kernel_launch(void* const* d_in, const int* in_sizes, int n_in,
                              void* d_out, int out_size, void* d_ws, size_t ws_size,
                              hipStream_t stream) {
    const int*   qtok = (const int*)d_in[0];
    const int*   dtok = (const int*)d_in[1];
    const float* emb  = (const float*)d_in[2];
    const float* fcw  = (const float*)d_in[3];
    float* out = (float*)d_out;
    float* ws  = (float*)d_ws;

    int B = in_sizes[0] / QN;                  // 512
    knrm_probe<0><<<B, 512, 0, stream>>>(qtok, dtok, emb, fcw, out);        // full, real out
    knrm_probe<1><<<B, 512, 0, stream>>>(qtok, dtok, emb, fcw, ws);         // no-eval
    knrm_probe<2><<<B, 512, 0, stream>>>(qtok, dtok, emb, fcw, ws + 1024);  // no-stage
    knrm_probe<3><<<B, 512, 0, stream>>>(qtok, dtok, emb, fcw, ws + 2048);  // no-reduce
}

// Round 16
// 21.374 us; speedup vs baseline: 9.9679x; 9.9679x over previous
//
#include <hip/hip_runtime.h>
#include <hip/hip_bf16.h>

#define EDIM  128
#define QN    32
#define DN    256
#define NK    11
#define CHR   64    // d-rows per chunk (4 chunks)

typedef __attribute__((ext_vector_type(8))) short bf16x8;
typedef __attribute__((ext_vector_type(4))) float f32x4;

#define EXP2F(x) __builtin_amdgcn_exp2f(x)

template <int CTRL>
static __device__ inline float dpp_add(float x) {
    int y = __builtin_amdgcn_update_dpp(0, __float_as_int(x), CTRL, 0xF, 0xF, true);
    return x + __int_as_float(y);
}
static __device__ inline float sum16(float x) {
    x = dpp_add<0xB1>(x);
    x = dpp_add<0x4E>(x);
    x = dpp_add<0x124>(x);
    x = dpp_add<0x128>(x);
    return x;
}

static __device__ inline int swz(int r, int c) { return c ^ ((r & 7) << 4); }

static __device__ inline bf16x8 pack8(float4 a, float4 b) {
    union { bf16x8 v; __hip_bfloat16 h[8]; } u;
    u.h[0] = __float2bfloat16(a.x); u.h[1] = __float2bfloat16(a.y);
    u.h[2] = __float2bfloat16(a.z); u.h[3] = __float2bfloat16(a.w);
    u.h[4] = __float2bfloat16(b.x); u.h[5] = __float2bfloat16(b.y);
    u.h[6] = __float2bfloat16(b.z); u.h[7] = __float2bfloat16(b.w);
    return u.v;
}
static __device__ inline float sumsq8(float4 a, float4 b) {
    float s = a.x * a.x + a.y * a.y + a.z * a.z + a.w * a.w;
    s = fmaf(b.x, b.x, s); s = fmaf(b.y, b.y, s);
    s = fmaf(b.z, b.z, s); s = fmaf(b.w, b.w, s);
    return s;
}

// ---------------- fused kernel: one 8-wave block per batch, 4-chunk d pipeline ----------------
// LDS ~24.5 KB -> 3-4 blocks/CU (vs 2). Chunk c+1 loads issued before eval of chunk c.
__global__ __launch_bounds__(512, 4) void knrm_fused(const int* __restrict__ qtok,
                                                     const int* __restrict__ dtok,
                                                     const float* __restrict__ emb,
                                                     const float* __restrict__ fcw,
                                                     float* __restrict__ out) {
    __shared__ __align__(16) unsigned short dbuf[CHR * EDIM];  // 16 KB; overlaid by part at end
    __shared__ __align__(16) unsigned short qbuf[QN * EDIM];   // 8 KB
    __shared__ float redS[8];

    // chain literals: Cj = inv_sqrt_2pi * e^{-4*T(j)}, T = 0,4,12,24,40
    const float C0 = 0.3989422804014327f;
    const float C1 = 7.30620157e-3f;
    const float C2 = 2.45119242e-6f;
    const float C3 = 1.50605972e-11f;
    const float C4 = 1.69484929e-18f;

    int b = blockIdx.x, tid = threadIdx.x;
    int w = tid >> 6, lane = tid & 63;
    int lr = lane & 15, lg = lane >> 4;
    int qt = w & 1, ds = w >> 1;

    const int* qtb = qtok + b * QN;
    const int* dtb = dtok + b * DN;

    // ---- all token loads upfront (small) ----
    int tq = qtb[(w << 2) + lg];
    int td[4][2];
    #pragma unroll
    for (int c = 0; c < 4; ++c)
        #pragma unroll
        for (int it = 0; it < 2; ++it)
            td[c][it] = dtb[c * CHR + (w << 3) + (it << 2) + lg];
    int tcurs[4], qtr[4];
    #pragma unroll
    for (int c = 0; c < 4; ++c) tcurs[c] = dtb[c * CHR + (ds << 4) + lr];
    #pragma unroll
    for (int r = 0; r < 4; ++r) qtr[r] = qtb[(qt << 4) + (lg << 2) + r];

    // ---- load q row + chunk 0 rows ----
    const float4* qsrc = (const float4*)(emb + (size_t)tq * EDIM) + lr * 2;
    float4 qv0 = qsrc[0], qv1 = qsrc[1];
    float4 ca[2][2];
    #pragma unroll
    for (int it = 0; it < 2; ++it) {
        const float4* s0 = (const float4*)(emb + (size_t)td[0][it] * EDIM) + lr * 2;
        ca[it][0] = s0[0]; ca[it][1] = s0[1];
    }

    // ---- process q row: normalize, pack, swizzled qbuf ----
    {
        int qr = (w << 2) + lg;
        float inv = 1.0f / sqrtf(sum16(sumsq8(qv0, qv1)));
        qv0.x *= inv; qv0.y *= inv; qv0.z *= inv; qv0.w *= inv;
        qv1.x *= inv; qv1.y *= inv; qv1.z *= inv; qv1.w *= inv;
        *(bf16x8*)((char*)qbuf + qr * 256 + swz(qr, lr * 16)) = pack8(qv0, qv1);
    }
    // ---- process chunk 0 rows -> dbuf ----
    #pragma unroll
    for (int it = 0; it < 2; ++it) {
        int rl = (w << 3) + (it << 2) + lg;
        float inv = 1.0f / sqrtf(sum16(sumsq8(ca[it][0], ca[it][1])));
        float4 v0 = ca[it][0], v1 = ca[it][1];
        v0.x *= inv; v0.y *= inv; v0.z *= inv; v0.w *= inv;
        v1.x *= inv; v1.y *= inv; v1.z *= inv; v1.w *= inv;
        *(bf16x8*)((char*)dbuf + rl * 256 + swz(rl, lr * 16)) = pack8(v0, v1);
    }
    __syncthreads();                                  // bar: q + chunk0 staged

    // ---- A fragments from qbuf ----
    bf16x8 A0, A1, A2, A3;
    {
        int qr = (qt << 4) + lr;
        const char* qb = (const char*)qbuf + qr * 256;
        A0 = *(const bf16x8*)(qb + swz(qr, lg * 16));
        A1 = *(const bf16x8*)(qb + swz(qr, lg * 16 + 64));
        A2 = *(const bf16x8*)(qb + swz(qr, lg * 16 + 128));
        A3 = *(const bf16x8*)(qb + swz(qr, lg * 16 + 192));
    }

    float kacc[4][NK];
    #pragma unroll
    for (int r = 0; r < 4; ++r)
        #pragma unroll
        for (int k = 0; k < NK; ++k) kacc[r][k] = 0.0f;

    // ---- chunk pipeline ----
    #pragma unroll
    for (int c = 0; c < 4; ++c) {
        // issue next chunk's loads (latency hides under eval below)
        float4 cb[2][2];
        if (c < 3) {
            #pragma unroll
            for (int it = 0; it < 2; ++it) {
                const float4* s0 = (const float4*)(emb + (size_t)td[c + 1][it] * EDIM) + lr * 2;
                cb[it][0] = s0[0]; cb[it][1] = s0[1];
            }
        }

        // eval chunk c: tile rows (local) rl = ds*16 + lr
        {
            int rl = (ds << 4) + lr;
            const char* db = (const char*)dbuf + rl * 256;
            bf16x8 B0 = *(const bf16x8*)(db + swz(rl, lg * 16));
            bf16x8 B1 = *(const bf16x8*)(db + swz(rl, lg * 16 + 64));
            bf16x8 B2 = *(const bf16x8*)(db + swz(rl, lg * 16 + 128));
            bf16x8 B3 = *(const bf16x8*)(db + swz(rl, lg * 16 + 192));
            int tcur = tcurs[c];

            f32x4 acc = {0.0f, 0.0f, 0.0f, 0.0f};
            acc = __builtin_amdgcn_mfma_f32_16x16x32_bf16(A0, B0, acc, 0, 0, 0);
            acc = __builtin_amdgcn_mfma_f32_16x16x32_bf16(A1, B1, acc, 0, 0, 0);
            acc = __builtin_amdgcn_mfma_f32_16x16x32_bf16(A2, B2, acc, 0, 0, 0);
            acc = __builtin_amdgcn_mfma_f32_16x16x32_bf16(A3, B3, acc, 0, 0, 0);

            bool dok = (tcur > 0);
            float mc = dok ? C0 : 0.0f;
            #pragma unroll
            for (int r = 0; r < 4; ++r) {
                float t2 = acc[r];                            // rows pre-normalized
                kacc[r][0] += (tcur == qtr[r]) ? mc : 0.0f;   // K0: exact token match
                float d  = t2 - 0.1f;
                float g  = EXP2F(d * d * -72.1347520f);       // K5 shape
                g = dok ? g : 0.0f;
                float Em = EXP2F(t2 * -28.8539008f);
                float Ep = EXP2F(t2 *  28.8539008f);
                float h = g;
                kacc[r][5]  += h * C0;
                h *= Em; kacc[r][6]  += h * C0;
                h *= Em; kacc[r][7]  += h * C1;
                h *= Em; kacc[r][8]  += h * C2;
                h *= Em; kacc[r][9]  += h * C3;
                h *= Em; kacc[r][10] += h * C4;
                h = g;
                h *= Ep; kacc[r][4]  += h * C1;
                h *= Ep; kacc[r][3]  += h * C2;
                h *= Ep; kacc[r][2]  += h * C3;
                h *= Ep; kacc[r][1]  += h * C4;
            }
        }
        __syncthreads();                              // all reads of dbuf done

        if (c < 3) {
            #pragma unroll
            for (int it = 0; it < 2; ++it) {
                int rl = (w << 3) + (it << 2) + lg;
                float inv = 1.0f / sqrtf(sum16(sumsq8(cb[it][0], cb[it][1])));
                float4 v0 = cb[it][0], v1 = cb[it][1];
                v0.x *= inv; v0.y *= inv; v0.z *= inv; v0.w *= inv;
                v1.x *= inv; v1.y *= inv; v1.z *= inv; v1.w *= inv;
                *(bf16x8*)((char*)dbuf + rl * 256 + swz(rl, lr * 16)) = pack8(v0, v1);
            }
            __syncthreads();                          // chunk c+1 staged
        }
    }

    // ---- DPP reduce over 16 doc-columns; overlay partials on dbuf ----
    float* part = (float*)dbuf;                       // safe: post-eval barrier passed
    #pragma unroll
    for (int r = 0; r < 4; ++r)
        #pragma unroll
        for (int k = 0; k < NK; ++k) kacc[r][k] = sum16(kacc[r][k]);
    if (lr == 0) {
        float* pw = part + w * (16 * NK) + (lg << 2) * NK;
        #pragma unroll
        for (int r = 0; r < 4; ++r)
            #pragma unroll
            for (int k = 0; k < NK; ++k)
                pw[r * NK + k] = kacc[r][k];
    }
    __syncthreads();                                  // partials visible

    // ---- combine 4 dspans, log-pool, weighted sum -> out[b] ----
    float total = 0.0f;
    if (tid < QN * NK) {
        int q = tid / NK, k = tid - (tid / NK) * NK;
        int qt2 = q >> 4, row = q & 15;
        const float* pb = part + qt2 * (16 * NK) + row * NK + k;
        float v = pb[0] + pb[2 * 16 * NK] + pb[4 * 16 * NK] + pb[6 * 16 * NK];
        float m = (qtb[q] > 0) ? 1.0f : 0.0f;
        total = m * fcw[k] * __logf(fmaxf(v, 1e-10f));
    }
    #pragma unroll
    for (int off = 32; off; off >>= 1) total += __shfl_xor(total, off);
    if (lane == 0) redS[w] = total;
    __syncthreads();
    if (tid == 0) {
        float s = 0.0f;
        #pragma unroll
        for (int i = 0; i < 8; ++i) s += redS[i];
        out[b] = s;
    }
}

extern "C" void kernel_launch(void* const* d_in, const int* in_sizes, int n_in,
                              void* d_out, int out_size, void* d_ws, size_t ws_size,
                              hipStream_t stream) {
    const int*   qtok = (const int*)d_in[0];
    const int*   dtok = (const int*)d_in[1];
    const float* emb  = (const float*)d_in[2];
    const float* fcw  = (const float*)d_in[3];
    float* out = (float*)d_out;

    int B = in_sizes[0] / QN;                  // 512
    knrm_fused<<<B, 512, 0, stream>>>(qtok, dtok, emb, fcw, out);
}